// Round 7
// baseline (303.958 us; speedup 1.0000x reference)
//
#include <hip/hip_runtime.h>
#include <hip/hip_bf16.h>

// QuantizedLinear: y[m][n] = scale * sum_k x[m][k]*(q[n][k]-zp) + bias[n]
// M=8192, N=4096, K=4096. (q-zp) integer in [-255,255] -> exact in bf16.
// cvt passes -> 256^2 bf16 MFMA GEMM, ONE barrier per K-tile.
// A triple-buffered + B double-buffered (160KB LDS) -> zero same-buffer WAR
// -> no lgkm drains; compiler-counted lgkm waits overlap ds_reads with MFMA.

typedef __attribute__((ext_vector_type(8))) __bf16 bf16x8;
typedef __attribute__((ext_vector_type(4))) float f32x4;
typedef __attribute__((ext_vector_type(4))) int i32x4;
typedef __attribute__((ext_vector_type(8))) unsigned short u16x8;

#define M_DIM 8192
#define N_DIM 4096
#define K_DIM 4096
#define BM 256
#define BN 256
#define BK 64
#define NT (K_DIM / BK)

#define MFMA16(A, B, C) __builtin_amdgcn_mfma_f32_16x16x32_bf16(A, B, C, 0, 0, 0)

__device__ __forceinline__ unsigned short f2bf(float f) {
  __hip_bfloat16 h = __float2bfloat16(f);
  unsigned short u;
  __builtin_memcpy(&u, &h, 2);
  return u;
}

// ---- conversion pass 1: x fp32 -> bf16 ----
__global__ __launch_bounds__(256) void cvt_x_kernel(const float* __restrict__ x,
                                                    unsigned short* __restrict__ out) {
  size_t i = (size_t)blockIdx.x * 256 + threadIdx.x;
  f32x4 a = ((const f32x4*)x)[2 * i];
  f32x4 b = ((const f32x4*)x)[2 * i + 1];
  u16x8 o;
  o[0] = f2bf(a[0]); o[1] = f2bf(a[1]); o[2] = f2bf(a[2]); o[3] = f2bf(a[3]);
  o[4] = f2bf(b[0]); o[5] = f2bf(b[1]); o[6] = f2bf(b[2]); o[7] = f2bf(b[3]);
  *(u16x8*)(out + 8 * i) = o;
}

// ---- conversion pass 2: w = (float)q - zp -> bf16 (exact) ----
__global__ __launch_bounds__(256) void cvt_w_kernel(const int* __restrict__ q,
                                                    const float* __restrict__ zp_ptr,
                                                    unsigned short* __restrict__ out) {
  const float zp = *zp_ptr;
  size_t i = (size_t)blockIdx.x * 256 + threadIdx.x;
  i32x4 a = ((const i32x4*)q)[2 * i];
  i32x4 b = ((const i32x4*)q)[2 * i + 1];
  u16x8 o;
  o[0] = f2bf((float)a[0] - zp); o[1] = f2bf((float)a[1] - zp);
  o[2] = f2bf((float)a[2] - zp); o[3] = f2bf((float)a[3] - zp);
  o[4] = f2bf((float)b[0] - zp); o[5] = f2bf((float)b[1] - zp);
  o[6] = f2bf((float)b[2] - zp); o[7] = f2bf((float)b[3] - zp);
  *(u16x8*)(out + 8 * i) = o;
}

// Stage one half-tile (128 rows x 64 bf16 = 16KB): 8 waves x 2 chunks x 1KB.
// Per-thread inverse-swizzled source offsets folded into s0/s1.
__device__ __forceinline__ void stage2(const char* s0, const char* s1, char* ldsT,
                                       int h, int Ti, int chunk0, int chunk1) {
  const size_t off = (size_t)Ti * 128 + (size_t)h * 1048576;
  __builtin_amdgcn_global_load_lds(
      (const __attribute__((address_space(1))) void*)(s0 + off),
      (__attribute__((address_space(3))) void*)(ldsT + h * 16384 + chunk0), 16, 0, 0);
  __builtin_amdgcn_global_load_lds(
      (const __attribute__((address_space(1))) void*)(s1 + off),
      (__attribute__((address_space(3))) void*)(ldsT + h * 16384 + chunk1), 16, 0, 0);
}

// One K-tile, single trailing barrier. Reads and MFMAs free-flow; the
// compiler inserts counted lgkm waits, so LDS service overlaps MFMA.
// stA/stB are NEVER the buffers being read this tile (3-buf A / 2-buf B).
__device__ __forceinline__ void ktile(
    int T,
    const char* paK0, const char* paK1, const char* pbK0, const char* pbK1,
    char* stA, char* stB,
    const char* srcA0, const char* srcA1, const char* srcB0, const char* srcB1,
    int chunk0, int chunk1, f32x4 (&acc)[8][4]) {
  bf16x8 af[4][2], b0f[2][2], b1f[2][2];

  // reads: a_lo (8), b0 (4), b1 (4)
#pragma unroll
  for (int fi = 0; fi < 4; ++fi) {
    af[fi][0] = *(const bf16x8*)(paK0 + fi * 2048);
    af[fi][1] = *(const bf16x8*)(paK1 + fi * 2048);
  }
#pragma unroll
  for (int fj = 0; fj < 2; ++fj) {
    b0f[fj][0] = *(const bf16x8*)(pbK0 + fj * 2048);
    b0f[fj][1] = *(const bf16x8*)(pbK1 + fj * 2048);
    b1f[fj][0] = *(const bf16x8*)(pbK0 + 4096 + fj * 2048);
    b1f[fj][1] = *(const bf16x8*)(pbK1 + 4096 + fj * 2048);
  }
  if (T < NT - 1) {
    stage2(srcB0, srcB1, stB, 0, T + 1, chunk0, chunk1);
    stage2(srcB0, srcB1, stB, 1, T + 1, chunk0, chunk1);
  }
  // MFMA Q(0,0)+Q(0,1) (32)
#pragma unroll
  for (int fi = 0; fi < 4; ++fi)
#pragma unroll
    for (int fj = 0; fj < 2; ++fj) {
      acc[fi][fj]     = MFMA16(af[fi][0], b0f[fj][0], acc[fi][fj]);
      acc[fi][fj]     = MFMA16(af[fi][1], b0f[fj][1], acc[fi][fj]);
      acc[fi][2 + fj] = MFMA16(af[fi][0], b1f[fj][0], acc[fi][2 + fj]);
      acc[fi][2 + fj] = MFMA16(af[fi][1], b1f[fj][1], acc[fi][2 + fj]);
    }
  // reads: a_hi (8, reuse af regs)
#pragma unroll
  for (int fi = 0; fi < 4; ++fi) {
    af[fi][0] = *(const bf16x8*)(paK0 + 8192 + fi * 2048);
    af[fi][1] = *(const bf16x8*)(paK1 + 8192 + fi * 2048);
  }
  if (T < NT - 2) {
    stage2(srcA0, srcA1, stA, 0, T + 2, chunk0, chunk1);
    stage2(srcA0, srcA1, stA, 1, T + 2, chunk0, chunk1);
  }
  // MFMA Q(1,1)+Q(1,0) (32)
#pragma unroll
  for (int fi = 0; fi < 4; ++fi)
#pragma unroll
    for (int fj = 0; fj < 2; ++fj) {
      acc[4 + fi][2 + fj] = MFMA16(af[fi][0], b1f[fj][0], acc[4 + fi][2 + fj]);
      acc[4 + fi][2 + fj] = MFMA16(af[fi][1], b1f[fj][1], acc[4 + fi][2 + fj]);
      acc[4 + fi][fj]     = MFMA16(af[fi][0], b0f[fj][0], acc[4 + fi][fj]);
      acc[4 + fi][fj]     = MFMA16(af[fi][1], b0f[fj][1], acc[4 + fi][fj]);
    }
  // tile-end: counted vmcnt publishes "tile T+1 landed"; single barrier.
  if (T < NT - 2) asm volatile("s_waitcnt vmcnt(4)" ::: "memory");
  else            asm volatile("s_waitcnt vmcnt(0)" ::: "memory");
  __builtin_amdgcn_s_barrier();
  asm volatile("" ::: "memory");
}

// ---- 256x256 GEMM, 1 barrier/K-tile, A 3-buf + B 2-buf (160KB LDS) ----
__global__ __launch_bounds__(512, 2) void gemm8_kernel(
    const unsigned short* __restrict__ A, const unsigned short* __restrict__ B,
    const float* __restrict__ scale_ptr, const float* __restrict__ bias,
    float* __restrict__ C) {
  __shared__ __align__(16) char lds[163840];  // A0,A1,A2 @0/32K/64K; B0,B1 @96K/128K

  const int t = threadIdx.x;
  const int lane = t & 63;
  const int w = t >> 6;      // 0..7
  const int wm = w >> 2;     // 0..1
  const int wn = w & 3;      // 0..3
  const int ll = lane & 15;
  const int lh = lane >> 4;

  // T1: bijective XCD swizzle (nwg = 512, 512 % 8 == 0)
  const int nwg = gridDim.x * gridDim.y;
  const int flat = blockIdx.y * gridDim.x + blockIdx.x;
  const int per = nwg >> 3;
  const int sw = (flat & 7) * per + (flat >> 3);
  const int tn = sw & (N_DIM / BN - 1);
  const int tm = sw / (N_DIM / BN);
  const size_t gm0 = (size_t)tm * BM;
  const size_t gn0 = (size_t)tn * BN;

  char* lA0 = (char*)lds;
  char* lA1 = (char*)lds + 32768;
  char* lA2 = (char*)lds + 65536;
  char* lB0 = (char*)lds + 98304;
  char* lB1 = (char*)lds + 131072;

  // Fragment-read bases (swizzle folded to per-thread constants).
  const int sbase = (lh * 16) ^ ((ll & 7) << 4);
  const int aoff = wm * 16384 + ll * 128;
  const int boff = wn * 8192 + ll * 128;
  const char* pA0k0 = lA0 + aoff + sbase;       const char* pA0k1 = lA0 + aoff + (sbase ^ 64);
  const char* pA1k0 = lA1 + aoff + sbase;       const char* pA1k1 = lA1 + aoff + (sbase ^ 64);
  const char* pA2k0 = lA2 + aoff + sbase;       const char* pA2k1 = lA2 + aoff + (sbase ^ 64);
  const char* pB0k0 = lB0 + boff + sbase;       const char* pB0k1 = lB0 + boff + (sbase ^ 64);
  const char* pB1k0 = lB1 + boff + sbase;       const char* pB1k1 = lB1 + boff + (sbase ^ 64);

  // Staging: per-thread inverse-swizzled row/col constants.
  const int rowS0 = w * 16 + (lane >> 3);
  const int rowS1 = w * 16 + 8 + (lane >> 3);
  const int colSB = ((lane & 7) * 16) ^ (((lane >> 3) & 7) << 4);
  const int chunk0 = w * 2048;
  const int chunk1 = w * 2048 + 1024;
  const char* srcA0 = (const char*)A + (gm0 + rowS0) * (size_t)(K_DIM * 2) + colSB;
  const char* srcA1 = (const char*)A + (gm0 + rowS1) * (size_t)(K_DIM * 2) + colSB;
  const char* srcB0 = (const char*)B + (gn0 + rowS0) * (size_t)(K_DIM * 2) + colSB;
  const char* srcB1 = (const char*)B + (gn0 + rowS1) * (size_t)(K_DIM * 2) + colSB;

  f32x4 acc[8][4] = {};  // [mh*4+fi][nh*2+fj]

  // ---- prologue: A(0)->A0, B(0)->B0, A(1)->A1 (12 loads) ----
  stage2(srcA0, srcA1, lA0, 0, 0, chunk0, chunk1);
  stage2(srcA0, srcA1, lA0, 1, 0, chunk0, chunk1);
  stage2(srcB0, srcB1, lB0, 0, 0, chunk0, chunk1);
  stage2(srcB0, srcB1, lB0, 1, 0, chunk0, chunk1);
  stage2(srcA0, srcA1, lA1, 0, 1, chunk0, chunk1);
  stage2(srcA0, srcA1, lA1, 1, 1, chunk0, chunk1);
  asm volatile("s_waitcnt vmcnt(4)" ::: "memory");  // A0,B0 landed; A1 in flight
  __builtin_amdgcn_s_barrier();
  asm volatile("" ::: "memory");

  // Buffer rotation period 6: tile T reads A[T%3], B[T%2];
  // stages B(T+1)->B[(T+1)%2], A(T+2)->A[(T+2)%3].
  for (int T6 = 0; T6 < NT - 4; T6 += 6) {
    ktile(T6 + 0, pA0k0, pA0k1, pB0k0, pB0k1, lA2, lB1, srcA0, srcA1, srcB0, srcB1, chunk0, chunk1, acc);
    ktile(T6 + 1, pA1k0, pA1k1, pB1k0, pB1k1, lA0, lB0, srcA0, srcA1, srcB0, srcB1, chunk0, chunk1, acc);
    ktile(T6 + 2, pA2k0, pA2k1, pB0k0, pB0k1, lA1, lB1, srcA0, srcA1, srcB0, srcB1, chunk0, chunk1, acc);
    ktile(T6 + 3, pA0k0, pA0k1, pB1k0, pB1k1, lA2, lB0, srcA0, srcA1, srcB0, srcB1, chunk0, chunk1, acc);
    ktile(T6 + 4, pA1k0, pA1k1, pB0k0, pB0k1, lA0, lB1, srcA0, srcA1, srcB0, srcB1, chunk0, chunk1, acc);
    ktile(T6 + 5, pA2k0, pA2k1, pB1k0, pB1k1, lA1, lB0, srcA0, srcA1, srcB0, srcB1, chunk0, chunk1, acc);
  }
  // tail: T = 60..63 (60%6==0)
  ktile(NT - 4, pA0k0, pA0k1, pB0k0, pB0k1, lA2, lB1, srcA0, srcA1, srcB0, srcB1, chunk0, chunk1, acc);
  ktile(NT - 3, pA1k0, pA1k1, pB1k0, pB1k1, lA0, lB0, srcA0, srcA1, srcB0, srcB1, chunk0, chunk1, acc);
  ktile(NT - 2, pA2k0, pA2k1, pB0k0, pB0k1, lA1, lB1, srcA0, srcA1, srcB0, srcB1, chunk0, chunk1, acc);
  ktile(NT - 1, pA0k0, pA0k1, pB1k0, pB1k1, lA2, lB0, srcA0, srcA1, srcB0, srcB1, chunk0, chunk1, acc);

  // ---- epilogue: y = scale*acc + bias ----
  const float sc = *scale_ptr;
#pragma unroll
  for (int nh = 0; nh < 2; ++nh)
#pragma unroll
    for (int fj = 0; fj < 2; ++fj) {
      const size_t col = gn0 + wn * 64 + nh * 32 + fj * 16 + ll;
      const float bv = bias[col];
#pragma unroll
      for (int mh = 0; mh < 2; ++mh)
#pragma unroll
        for (int fi = 0; fi < 4; ++fi) {
          const size_t row0 = gm0 + wm * 128 + mh * 64 + fi * 16 + lh * 4;
          const f32x4 v = acc[mh * 4 + fi][nh * 2 + fj];
#pragma unroll
          for (int r = 0; r < 4; ++r)
            C[(row0 + r) * N_DIM + col] = sc * v[r] + bv;
        }
    }
}

// ---- fallback (small ws): fused-conversion 128^2 GEMM, known-correct from R0 ----
__global__ __launch_bounds__(256, 2) void gemm_fallback_kernel(
    const float* __restrict__ Aptr, const int* __restrict__ Wptr,
    const float* __restrict__ scale_ptr, const float* __restrict__ zp_ptr,
    const float* __restrict__ bias, float* __restrict__ C) {
  __shared__ unsigned short As[128 * 32];
  __shared__ unsigned short Ws[128 * 32];
  const int t = threadIdx.x;
  const int lane = t & 63;
  const int w = t >> 6;
  const int wm = w >> 1, wn = w & 1;
  const size_t gm0 = (size_t)blockIdx.y * 128;
  const size_t gn0 = (size_t)blockIdx.x * 128;
  f32x4 acc[4][4] = {};
  const float zp = *zp_ptr;
  for (int k0 = 0; k0 < K_DIM; k0 += 32) {
    __syncthreads();
    const int row = t >> 1;
    const int kh = (t & 1) * 16;
    const float* sa = Aptr + (gm0 + row) * (size_t)K_DIM + k0 + kh;
    f32x4 a0 = ((const f32x4*)sa)[0], a1 = ((const f32x4*)sa)[1];
    f32x4 a2 = ((const f32x4*)sa)[2], a3 = ((const f32x4*)sa)[3];
    u16x8 o0, o1;
    o0[0] = f2bf(a0[0]); o0[1] = f2bf(a0[1]); o0[2] = f2bf(a0[2]); o0[3] = f2bf(a0[3]);
    o0[4] = f2bf(a1[0]); o0[5] = f2bf(a1[1]); o0[6] = f2bf(a1[2]); o0[7] = f2bf(a1[3]);
    o1[0] = f2bf(a2[0]); o1[1] = f2bf(a2[1]); o1[2] = f2bf(a2[2]); o1[3] = f2bf(a2[3]);
    o1[4] = f2bf(a3[0]); o1[5] = f2bf(a3[1]); o1[6] = f2bf(a3[2]); o1[7] = f2bf(a3[3]);
    *(u16x8*)&As[row * 32 + kh] = o0;
    *(u16x8*)&As[row * 32 + kh + 8] = o1;
    const int* sw = Wptr + (gn0 + row) * (size_t)K_DIM + k0 + kh;
    i32x4 w0 = ((const i32x4*)sw)[0], w1 = ((const i32x4*)sw)[1];
    i32x4 w2 = ((const i32x4*)sw)[2], w3 = ((const i32x4*)sw)[3];
    u16x8 p0, p1;
    p0[0] = f2bf((float)w0[0] - zp); p0[1] = f2bf((float)w0[1] - zp);
    p0[2] = f2bf((float)w0[2] - zp); p0[3] = f2bf((float)w0[3] - zp);
    p0[4] = f2bf((float)w1[0] - zp); p0[5] = f2bf((float)w1[1] - zp);
    p0[6] = f2bf((float)w1[2] - zp); p0[7] = f2bf((float)w1[3] - zp);
    p1[0] = f2bf((float)w2[0] - zp); p1[1] = f2bf((float)w2[1] - zp);
    p1[2] = f2bf((float)w2[2] - zp); p1[3] = f2bf((float)w2[3] - zp);
    p1[4] = f2bf((float)w3[0] - zp); p1[5] = f2bf((float)w3[1] - zp);
    p1[6] = f2bf((float)w3[2] - zp); p1[7] = f2bf((float)w3[3] - zp);
    *(u16x8*)&Ws[row * 32 + kh] = p0;
    *(u16x8*)&Ws[row * 32 + kh + 8] = p1;
    __syncthreads();
    bf16x8 af[4], bfr[4];
#pragma unroll
    for (int f = 0; f < 4; ++f) {
      af[f] = *(const bf16x8*)&As[(wm * 64 + f * 16 + (lane & 15)) * 32 + (lane >> 4) * 8];
      bfr[f] = *(const bf16x8*)&Ws[(wn * 64 + f * 16 + (lane & 15)) * 32 + (lane >> 4) * 8];
    }
#pragma unroll
    for (int i = 0; i < 4; ++i)
#pragma unroll
      for (int j = 0; j < 4; ++j)
        acc[i][j] = MFMA16(af[i], bfr[j], acc[i][j]);
  }
  const float sc = *scale_ptr;
#pragma unroll
  for (int i = 0; i < 4; ++i) {
    const int rbase = wm * 64 + i * 16 + ((lane >> 4) << 2);
#pragma unroll
    for (int j = 0; j < 4; ++j) {
      const size_t col = gn0 + wn * 64 + j * 16 + (lane & 15);
      const float bv = bias[col];
#pragma unroll
      for (int r = 0; r < 4; ++r)
        C[(gm0 + rbase + r) * N_DIM + col] = sc * acc[i][j][r] + bv;
    }
  }
}

extern "C" void kernel_launch(void* const* d_in, const int* in_sizes, int n_in,
                              void* d_out, int out_size, void* d_ws, size_t ws_size,
                              hipStream_t stream) {
  const float* x = (const float*)d_in[0];
  const int* q = (const int*)d_in[1];
  const float* scale = (const float*)d_in[2];
  const float* zp = (const float*)d_in[3];
  const float* bias = (const float*)d_in[4];
  float* out = (float*)d_out;

  const size_t needA = (size_t)M_DIM * K_DIM * 2;  // 64 MiB
  const size_t needW = (size_t)N_DIM * K_DIM * 2;  // 32 MiB

  if (ws_size >= needA + needW) {
    unsigned short* Abf = (unsigned short*)d_ws;
    unsigned short* Wbf = (unsigned short*)((char*)d_ws + needA);
    cvt_x_kernel<<<(M_DIM * (size_t)K_DIM) / (8 * 256), 256, 0, stream>>>(x, Abf);
    cvt_w_kernel<<<(N_DIM * (size_t)K_DIM) / (8 * 256), 256, 0, stream>>>(q, zp, Wbf);
    dim3 grid(N_DIM / BN, M_DIM / BM);  // 16 x 32 = 512
    gemm8_kernel<<<grid, 512, 0, stream>>>(Abf, Wbf, scale, bias, out);
  } else {
    dim3 grid(N_DIM / 128, M_DIM / 128);
    gemm_fallback_kernel<<<grid, 256, 0, stream>>>(x, q, scale, zp, bias, out);
  }
}

// Round 9
// 266.895 us; speedup vs baseline: 1.1389x; 1.1389x over previous
//
#include <hip/hip_runtime.h>
#include <hip/hip_bf16.h>

// QuantizedLinear: y[m][n] = scale * sum_k x[m][k]*(q[n][k]-zp) + bias[n]
// M=8192, N=4096, K=4096. (q-zp) integer in [-255,255] -> exact in bf16.
// cvt passes -> 256^2 bf16 MFMA GEMM, 2 barrier intervals per K-tile.
// A 3-buf + B 2-buf (160KB LDS). lgkmcnt(0) drained AFTER each barrier
// (m201 placement): reads are serviced while the wave waits at the barrier
// and while other waves MFMA. WAR safety proven by buffer-disjointness
// under <=1-barrier wave skew; RAW via all-waves vmcnt(4) pre-barrier.

typedef __attribute__((ext_vector_type(8))) __bf16 bf16x8;
typedef __attribute__((ext_vector_type(4))) float f32x4;
typedef __attribute__((ext_vector_type(4))) int i32x4;
typedef __attribute__((ext_vector_type(8))) unsigned short u16x8;

#define M_DIM 8192
#define N_DIM 4096
#define K_DIM 4096
#define BM 256
#define BN 256
#define BK 64
#define NT (K_DIM / BK)

#define MFMA16(A, B, C) __builtin_amdgcn_mfma_f32_16x16x32_bf16(A, B, C, 0, 0, 0)

__device__ __forceinline__ unsigned short f2bf(float f) {
  __hip_bfloat16 h = __float2bfloat16(f);
  unsigned short u;
  __builtin_memcpy(&u, &h, 2);
  return u;
}

// ---- conversion pass 1: x fp32 -> bf16 ----
__global__ __launch_bounds__(256) void cvt_x_kernel(const float* __restrict__ x,
                                                    unsigned short* __restrict__ out) {
  size_t i = (size_t)blockIdx.x * 256 + threadIdx.x;
  f32x4 a = ((const f32x4*)x)[2 * i];
  f32x4 b = ((const f32x4*)x)[2 * i + 1];
  u16x8 o;
  o[0] = f2bf(a[0]); o[1] = f2bf(a[1]); o[2] = f2bf(a[2]); o[3] = f2bf(a[3]);
  o[4] = f2bf(b[0]); o[5] = f2bf(b[1]); o[6] = f2bf(b[2]); o[7] = f2bf(b[3]);
  *(u16x8*)(out + 8 * i) = o;
}

// ---- conversion pass 2: w = (float)q - zp -> bf16 (exact) ----
__global__ __launch_bounds__(256) void cvt_w_kernel(const int* __restrict__ q,
                                                    const float* __restrict__ zp_ptr,
                                                    unsigned short* __restrict__ out) {
  const float zp = *zp_ptr;
  size_t i = (size_t)blockIdx.x * 256 + threadIdx.x;
  i32x4 a = ((const i32x4*)q)[2 * i];
  i32x4 b = ((const i32x4*)q)[2 * i + 1];
  u16x8 o;
  o[0] = f2bf((float)a[0] - zp); o[1] = f2bf((float)a[1] - zp);
  o[2] = f2bf((float)a[2] - zp); o[3] = f2bf((float)a[3] - zp);
  o[4] = f2bf((float)b[0] - zp); o[5] = f2bf((float)b[1] - zp);
  o[6] = f2bf((float)b[2] - zp); o[7] = f2bf((float)b[3] - zp);
  *(u16x8*)(out + 8 * i) = o;
}

// Stage one half-tile (128 rows x 64 bf16 = 16KB): 8 waves x 2 chunks x 1KB.
// Per-thread inverse-swizzled source offsets folded into s0/s1.
__device__ __forceinline__ void stage2(const char* s0, const char* s1, char* ldsT,
                                       int h, int Ti, int chunk0, int chunk1) {
  const size_t off = (size_t)Ti * 128 + (size_t)h * 1048576;
  __builtin_amdgcn_global_load_lds(
      (const __attribute__((address_space(1))) void*)(s0 + off),
      (__attribute__((address_space(3))) void*)(ldsT + h * 16384 + chunk0), 16, 0, 0);
  __builtin_amdgcn_global_load_lds(
      (const __attribute__((address_space(1))) void*)(s1 + off),
      (__attribute__((address_space(3))) void*)(ldsT + h * 16384 + chunk1), 16, 0, 0);
}

// One K-tile = 2 barrier intervals of 32 MFMA each.
// Interval pattern: {ds_reads; stage; [vmcnt]; BARRIER; lgkm0; sched_bar; MFMA}
__device__ __forceinline__ void ktile(
    int T,
    const char* paK0, const char* paK1, const char* pbK0, const char* pbK1,
    char* stA, char* stB,
    const char* srcA0, const char* srcA1, const char* srcB0, const char* srcB1,
    int chunk0, int chunk1, f32x4 (&acc)[8][4]) {
  bf16x8 af[4][2], b0f[2][2], b1f[2][2];

  // ==== interval 1: reads a_lo + b0 + b1; stage B(T+1); MFMA Q(0,0)+Q(0,1) ====
#pragma unroll
  for (int fi = 0; fi < 4; ++fi) {
    af[fi][0] = *(const bf16x8*)(paK0 + fi * 2048);
    af[fi][1] = *(const bf16x8*)(paK1 + fi * 2048);
  }
#pragma unroll
  for (int fj = 0; fj < 2; ++fj) {
    b0f[fj][0] = *(const bf16x8*)(pbK0 + fj * 2048);
    b0f[fj][1] = *(const bf16x8*)(pbK1 + fj * 2048);
    b1f[fj][0] = *(const bf16x8*)(pbK0 + 4096 + fj * 2048);
    b1f[fj][1] = *(const bf16x8*)(pbK1 + 4096 + fj * 2048);
  }
  if (T < NT - 1) {
    stage2(srcB0, srcB1, stB, 0, T + 1, chunk0, chunk1);
    stage2(srcB0, srcB1, stB, 1, T + 1, chunk0, chunk1);
  }
  __builtin_amdgcn_s_barrier();
  asm volatile("s_waitcnt lgkmcnt(0)" ::: "memory");
  __builtin_amdgcn_sched_barrier(0);
  __builtin_amdgcn_s_setprio(1);
#pragma unroll
  for (int fi = 0; fi < 4; ++fi)
#pragma unroll
    for (int fj = 0; fj < 2; ++fj) {
      acc[fi][fj] = MFMA16(af[fi][0], b0f[fj][0], acc[fi][fj]);
      acc[fi][fj] = MFMA16(af[fi][1], b0f[fj][1], acc[fi][fj]);
    }
#pragma unroll
  for (int fi = 0; fi < 4; ++fi)
#pragma unroll
    for (int fj = 0; fj < 2; ++fj) {
      acc[fi][2 + fj] = MFMA16(af[fi][0], b1f[fj][0], acc[fi][2 + fj]);
      acc[fi][2 + fj] = MFMA16(af[fi][1], b1f[fj][1], acc[fi][2 + fj]);
    }
  __builtin_amdgcn_s_setprio(0);

  // ==== interval 2: reads a_hi; stage A(T+2); vmcnt; MFMA Q(1,1)+Q(1,0) ====
#pragma unroll
  for (int fi = 0; fi < 4; ++fi) {
    af[fi][0] = *(const bf16x8*)(paK0 + 8192 + fi * 2048);
    af[fi][1] = *(const bf16x8*)(paK1 + 8192 + fi * 2048);
  }
  if (T < NT - 2) {
    stage2(srcA0, srcA1, stA, 0, T + 2, chunk0, chunk1);
    stage2(srcA0, srcA1, stA, 1, T + 2, chunk0, chunk1);
  }
  // Publishes tile T+1 (drains A(T+1)+B(T+1); leaves A(T+2) in flight).
  if (T < NT - 2) asm volatile("s_waitcnt vmcnt(4)" ::: "memory");
  else            asm volatile("s_waitcnt vmcnt(0)" ::: "memory");
  __builtin_amdgcn_s_barrier();
  asm volatile("s_waitcnt lgkmcnt(0)" ::: "memory");
  __builtin_amdgcn_sched_barrier(0);
  __builtin_amdgcn_s_setprio(1);
#pragma unroll
  for (int fi = 0; fi < 4; ++fi)
#pragma unroll
    for (int fj = 0; fj < 2; ++fj) {
      acc[4 + fi][2 + fj] = MFMA16(af[fi][0], b1f[fj][0], acc[4 + fi][2 + fj]);
      acc[4 + fi][2 + fj] = MFMA16(af[fi][1], b1f[fj][1], acc[4 + fi][2 + fj]);
    }
#pragma unroll
  for (int fi = 0; fi < 4; ++fi)
#pragma unroll
    for (int fj = 0; fj < 2; ++fj) {
      acc[4 + fi][fj] = MFMA16(af[fi][0], b0f[fj][0], acc[4 + fi][fj]);
      acc[4 + fi][fj] = MFMA16(af[fi][1], b0f[fj][1], acc[4 + fi][fj]);
    }
  __builtin_amdgcn_s_setprio(0);
}

// ---- 256x256 GEMM, 2 intervals/K-tile, A 3-buf + B 2-buf (160KB LDS) ----
__global__ __launch_bounds__(512, 2) void gemm8_kernel(
    const unsigned short* __restrict__ A, const unsigned short* __restrict__ B,
    const float* __restrict__ scale_ptr, const float* __restrict__ bias,
    float* __restrict__ C) {
  __shared__ __align__(16) char lds[163840];  // A0,A1,A2 @0/32K/64K; B0,B1 @96K/128K

  const int t = threadIdx.x;
  const int lane = t & 63;
  const int w = t >> 6;      // 0..7
  const int wm = w >> 2;     // 0..1
  const int wn = w & 3;      // 0..3
  const int ll = lane & 15;
  const int lh = lane >> 4;

  // T1: bijective XCD swizzle (nwg = 512, 512 % 8 == 0)
  const int nwg = gridDim.x * gridDim.y;
  const int flat = blockIdx.y * gridDim.x + blockIdx.x;
  const int per = nwg >> 3;
  const int sw = (flat & 7) * per + (flat >> 3);
  const int tn = sw & (N_DIM / BN - 1);
  const int tm = sw / (N_DIM / BN);
  const size_t gm0 = (size_t)tm * BM;
  const size_t gn0 = (size_t)tn * BN;

  char* lA0 = (char*)lds;
  char* lA1 = (char*)lds + 32768;
  char* lA2 = (char*)lds + 65536;
  char* lB0 = (char*)lds + 98304;
  char* lB1 = (char*)lds + 131072;

  // Fragment-read bases (swizzle folded to per-thread constants).
  const int sbase = (lh * 16) ^ ((ll & 7) << 4);
  const int aoff = wm * 16384 + ll * 128;
  const int boff = wn * 8192 + ll * 128;
  const char* pA0k0 = lA0 + aoff + sbase;  const char* pA0k1 = lA0 + aoff + (sbase ^ 64);
  const char* pA1k0 = lA1 + aoff + sbase;  const char* pA1k1 = lA1 + aoff + (sbase ^ 64);
  const char* pA2k0 = lA2 + aoff + sbase;  const char* pA2k1 = lA2 + aoff + (sbase ^ 64);
  const char* pB0k0 = lB0 + boff + sbase;  const char* pB0k1 = lB0 + boff + (sbase ^ 64);
  const char* pB1k0 = lB1 + boff + sbase;  const char* pB1k1 = lB1 + boff + (sbase ^ 64);

  // Staging: per-thread inverse-swizzled row/col constants.
  const int rowS0 = w * 16 + (lane >> 3);
  const int rowS1 = w * 16 + 8 + (lane >> 3);
  const int colSB = ((lane & 7) * 16) ^ (((lane >> 3) & 7) << 4);
  const int chunk0 = w * 2048;
  const int chunk1 = w * 2048 + 1024;
  const char* srcA0 = (const char*)A + (gm0 + rowS0) * (size_t)(K_DIM * 2) + colSB;
  const char* srcA1 = (const char*)A + (gm0 + rowS1) * (size_t)(K_DIM * 2) + colSB;
  const char* srcB0 = (const char*)B + (gn0 + rowS0) * (size_t)(K_DIM * 2) + colSB;
  const char* srcB1 = (const char*)B + (gn0 + rowS1) * (size_t)(K_DIM * 2) + colSB;

  f32x4 acc[8][4] = {};  // [mh*4+fi][nh*2+fj]

  // ---- prologue: A(0)->A0, B(0)->B0, A(1)->A1 (12 loads) ----
  stage2(srcA0, srcA1, lA0, 0, 0, chunk0, chunk1);
  stage2(srcA0, srcA1, lA0, 1, 0, chunk0, chunk1);
  stage2(srcB0, srcB1, lB0, 0, 0, chunk0, chunk1);
  stage2(srcB0, srcB1, lB0, 1, 0, chunk0, chunk1);
  stage2(srcA0, srcA1, lA1, 0, 1, chunk0, chunk1);
  stage2(srcA0, srcA1, lA1, 1, 1, chunk0, chunk1);
  asm volatile("s_waitcnt vmcnt(4)" ::: "memory");  // A0,B0 landed; A1 in flight
  __builtin_amdgcn_s_barrier();
  asm volatile("" ::: "memory");

  // Buffer rotation period 6: tile T reads A[T%3], B[T%2];
  // stages B(T+1)->B[(T+1)%2], A(T+2)->A[(T+2)%3].
  for (int T6 = 0; T6 < NT - 4; T6 += 6) {
    ktile(T6 + 0, pA0k0, pA0k1, pB0k0, pB0k1, lA2, lB1, srcA0, srcA1, srcB0, srcB1, chunk0, chunk1, acc);
    ktile(T6 + 1, pA1k0, pA1k1, pB1k0, pB1k1, lA0, lB0, srcA0, srcA1, srcB0, srcB1, chunk0, chunk1, acc);
    ktile(T6 + 2, pA2k0, pA2k1, pB0k0, pB0k1, lA1, lB1, srcA0, srcA1, srcB0, srcB1, chunk0, chunk1, acc);
    ktile(T6 + 3, pA0k0, pA0k1, pB1k0, pB1k1, lA2, lB0, srcA0, srcA1, srcB0, srcB1, chunk0, chunk1, acc);
    ktile(T6 + 4, pA1k0, pA1k1, pB0k0, pB0k1, lA0, lB1, srcA0, srcA1, srcB0, srcB1, chunk0, chunk1, acc);
    ktile(T6 + 5, pA2k0, pA2k1, pB1k0, pB1k1, lA1, lB0, srcA0, srcA1, srcB0, srcB1, chunk0, chunk1, acc);
  }
  // tail: T = 60..63 (60 % 6 == 0)
  ktile(NT - 4, pA0k0, pA0k1, pB0k0, pB0k1, lA2, lB1, srcA0, srcA1, srcB0, srcB1, chunk0, chunk1, acc);
  ktile(NT - 3, pA1k0, pA1k1, pB1k0, pB1k1, lA0, lB0, srcA0, srcA1, srcB0, srcB1, chunk0, chunk1, acc);
  ktile(NT - 2, pA2k0, pA2k1, pB0k0, pB0k1, lA1, lB1, srcA0, srcA1, srcB0, srcB1, chunk0, chunk1, acc);
  ktile(NT - 1, pA0k0, pA0k1, pB1k0, pB1k1, lA2, lB0, srcA0, srcA1, srcB0, srcB1, chunk0, chunk1, acc);

  // ---- epilogue: y = scale*acc + bias ----
  const float sc = *scale_ptr;
#pragma unroll
  for (int nh = 0; nh < 2; ++nh)
#pragma unroll
    for (int fj = 0; fj < 2; ++fj) {
      const size_t col = gn0 + wn * 64 + nh * 32 + fj * 16 + ll;
      const float bv = bias[col];
#pragma unroll
      for (int mh = 0; mh < 2; ++mh)
#pragma unroll
        for (int fi = 0; fi < 4; ++fi) {
          const size_t row0 = gm0 + wm * 128 + mh * 64 + fi * 16 + lh * 4;
          const f32x4 v = acc[mh * 4 + fi][nh * 2 + fj];
#pragma unroll
          for (int r = 0; r < 4; ++r)
            C[(row0 + r) * N_DIM + col] = sc * v[r] + bv;
        }
    }
}

// ---- fallback (small ws): fused-conversion 128^2 GEMM, known-correct from R0 ----
__global__ __launch_bounds__(256, 2) void gemm_fallback_kernel(
    const float* __restrict__ Aptr, const int* __restrict__ Wptr,
    const float* __restrict__ scale_ptr, const float* __restrict__ zp_ptr,
    const float* __restrict__ bias, float* __restrict__ C) {
  __shared__ unsigned short As[128 * 32];
  __shared__ unsigned short Ws[128 * 32];
  const int t = threadIdx.x;
  const int lane = t & 63;
  const int w = t >> 6;
  const int wm = w >> 1, wn = w & 1;
  const size_t gm0 = (size_t)blockIdx.y * 128;
  const size_t gn0 = (size_t)blockIdx.x * 128;
  f32x4 acc[4][4] = {};
  const float zp = *zp_ptr;
  for (int k0 = 0; k0 < K_DIM; k0 += 32) {
    __syncthreads();
    const int row = t >> 1;
    const int kh = (t & 1) * 16;
    const float* sa = Aptr + (gm0 + row) * (size_t)K_DIM + k0 + kh;
    f32x4 a0 = ((const f32x4*)sa)[0], a1 = ((const f32x4*)sa)[1];
    f32x4 a2 = ((const f32x4*)sa)[2], a3 = ((const f32x4*)sa)[3];
    u16x8 o0, o1;
    o0[0] = f2bf(a0[0]); o0[1] = f2bf(a0[1]); o0[2] = f2bf(a0[2]); o0[3] = f2bf(a0[3]);
    o0[4] = f2bf(a1[0]); o0[5] = f2bf(a1[1]); o0[6] = f2bf(a1[2]); o0[7] = f2bf(a1[3]);
    o1[0] = f2bf(a2[0]); o1[1] = f2bf(a2[1]); o1[2] = f2bf(a2[2]); o1[3] = f2bf(a2[3]);
    o1[4] = f2bf(a3[0]); o1[5] = f2bf(a3[1]); o1[6] = f2bf(a3[2]); o1[7] = f2bf(a3[3]);
    *(u16x8*)&As[row * 32 + kh] = o0;
    *(u16x8*)&As[row * 32 + kh + 8] = o1;
    const int* sw = Wptr + (gn0 + row) * (size_t)K_DIM + k0 + kh;
    i32x4 w0 = ((const i32x4*)sw)[0], w1 = ((const i32x4*)sw)[1];
    i32x4 w2 = ((const i32x4*)sw)[2], w3 = ((const i32x4*)sw)[3];
    u16x8 p0, p1;
    p0[0] = f2bf((float)w0[0] - zp); p0[1] = f2bf((float)w0[1] - zp);
    p0[2] = f2bf((float)w0[2] - zp); p0[3] = f2bf((float)w0[3] - zp);
    p0[4] = f2bf((float)w1[0] - zp); p0[5] = f2bf((float)w1[1] - zp);
    p0[6] = f2bf((float)w1[2] - zp); p0[7] = f2bf((float)w1[3] - zp);
    p1[0] = f2bf((float)w2[0] - zp); p1[1] = f2bf((float)w2[1] - zp);
    p1[2] = f2bf((float)w2[2] - zp); p1[3] = f2bf((float)w2[3] - zp);
    p1[4] = f2bf((float)w3[0] - zp); p1[5] = f2bf((float)w3[1] - zp);
    p1[6] = f2bf((float)w3[2] - zp); p1[7] = f2bf((float)w3[3] - zp);
    *(u16x8*)&Ws[row * 32 + kh] = p0;
    *(u16x8*)&Ws[row * 32 + kh + 8] = p1;
    __syncthreads();
    bf16x8 af[4], bfr[4];
#pragma unroll
    for (int f = 0; f < 4; ++f) {
      af[f] = *(const bf16x8*)&As[(wm * 64 + f * 16 + (lane & 15)) * 32 + (lane >> 4) * 8];
      bfr[f] = *(const bf16x8*)&Ws[(wn * 64 + f * 16 + (lane & 15)) * 32 + (lane >> 4) * 8];
    }
#pragma unroll
    for (int i = 0; i < 4; ++i)
#pragma unroll
      for (int j = 0; j < 4; ++j)
        acc[i][j] = MFMA16(af[i], bfr[j], acc[i][j]);
  }
  const float sc = *scale_ptr;
#pragma unroll
  for (int i = 0; i < 4; ++i) {
    const int rbase = wm * 64 + i * 16 + ((lane >> 4) << 2);
#pragma unroll
    for (int j = 0; j < 4; ++j) {
      const size_t col = gn0 + wn * 64 + j * 16 + (lane & 15);
      const float bv = bias[col];
#pragma unroll
      for (int r = 0; r < 4; ++r)
        C[(gm0 + rbase + r) * N_DIM + col] = sc * acc[i][j][r] + bv;
    }
  }
}

extern "C" void kernel_launch(void* const* d_in, const int* in_sizes, int n_in,
                              void* d_out, int out_size, void* d_ws, size_t ws_size,
                              hipStream_t stream) {
  const float* x = (const float*)d_in[0];
  const int* q = (const int*)d_in[1];
  const float* scale = (const float*)d_in[2];
  const float* zp = (const float*)d_in[3];
  const float* bias = (const float*)d_in[4];
  float* out = (float*)d_out;

  const size_t needA = (size_t)M_DIM * K_DIM * 2;  // 64 MiB
  const size_t needW = (size_t)N_DIM * K_DIM * 2;  // 32 MiB

  if (ws_size >= needA + needW) {
    unsigned short* Abf = (unsigned short*)d_ws;
    unsigned short* Wbf = (unsigned short*)((char*)d_ws + needA);
    cvt_x_kernel<<<(M_DIM * (size_t)K_DIM) / (8 * 256), 256, 0, stream>>>(x, Abf);
    cvt_w_kernel<<<(N_DIM * (size_t)K_DIM) / (8 * 256), 256, 0, stream>>>(q, zp, Wbf);
    dim3 grid(N_DIM / BN, M_DIM / BM);  // 16 x 32 = 512
    gemm8_kernel<<<grid, 512, 0, stream>>>(Abf, Wbf, scale, bias, out);
  } else {
    dim3 grid(N_DIM / 128, M_DIM / 128);
    gemm_fallback_kernel<<<grid, 256, 0, stream>>>(x, q, scale, zp, bias, out);
  }
}

// Round 10
// 265.739 us; speedup vs baseline: 1.1438x; 1.0044x over previous
//
#include <hip/hip_runtime.h>
#include <hip/hip_bf16.h>

// QuantizedLinear: y[m][n] = scale * sum_k x[m][k]*(q[n][k]-zp) + bias[n]
// M=8192, N=4096, K=4096. (q-zp) integer in [-255,255] -> exact in bf16.
// cvt passes -> 256^2 bf16 MFMA GEMM, 2 barrier intervals per K-tile,
// A 3-buf + B 2-buf (160KB LDS). v3: no blanket lgkm drains -- ds_reads are
// plain loads in CONSUMPTION ORDER; the compiler emits progressive counted
// lgkm waits so fragment service overlaps the MFMA clusters. Barriers carry
// pure compiler fences. vmcnt ledger identical to R9 (proven).
// WAR audit: all tile-T reads drain before the wave's next barrier arrival
// except a_hi (consumed post-bar2); a_hi vs stage A(T+3) is ordered by the
// mid-tile barrier of tile T+1 -- barrier #1 is load-bearing, do not remove.

typedef __attribute__((ext_vector_type(8))) __bf16 bf16x8;
typedef __attribute__((ext_vector_type(4))) float f32x4;
typedef __attribute__((ext_vector_type(4))) int i32x4;
typedef __attribute__((ext_vector_type(8))) unsigned short u16x8;

#define M_DIM 8192
#define N_DIM 4096
#define K_DIM 4096
#define BM 256
#define BN 256
#define BK 64
#define NT (K_DIM / BK)

#define MFMA16(A, B, C) __builtin_amdgcn_mfma_f32_16x16x32_bf16(A, B, C, 0, 0, 0)
#define FENCE() asm volatile("" ::: "memory")

__device__ __forceinline__ unsigned short f2bf(float f) {
  __hip_bfloat16 h = __float2bfloat16(f);
  unsigned short u;
  __builtin_memcpy(&u, &h, 2);
  return u;
}

// ---- conversion pass 1: x fp32 -> bf16 ----
__global__ __launch_bounds__(256) void cvt_x_kernel(const float* __restrict__ x,
                                                    unsigned short* __restrict__ out) {
  size_t i = (size_t)blockIdx.x * 256 + threadIdx.x;
  f32x4 a = ((const f32x4*)x)[2 * i];
  f32x4 b = ((const f32x4*)x)[2 * i + 1];
  u16x8 o;
  o[0] = f2bf(a[0]); o[1] = f2bf(a[1]); o[2] = f2bf(a[2]); o[3] = f2bf(a[3]);
  o[4] = f2bf(b[0]); o[5] = f2bf(b[1]); o[6] = f2bf(b[2]); o[7] = f2bf(b[3]);
  *(u16x8*)(out + 8 * i) = o;
}

// ---- conversion pass 2: w = (float)q - zp -> bf16 (exact) ----
__global__ __launch_bounds__(256) void cvt_w_kernel(const int* __restrict__ q,
                                                    const float* __restrict__ zp_ptr,
                                                    unsigned short* __restrict__ out) {
  const float zp = *zp_ptr;
  size_t i = (size_t)blockIdx.x * 256 + threadIdx.x;
  i32x4 a = ((const i32x4*)q)[2 * i];
  i32x4 b = ((const i32x4*)q)[2 * i + 1];
  u16x8 o;
  o[0] = f2bf((float)a[0] - zp); o[1] = f2bf((float)a[1] - zp);
  o[2] = f2bf((float)a[2] - zp); o[3] = f2bf((float)a[3] - zp);
  o[4] = f2bf((float)b[0] - zp); o[5] = f2bf((float)b[1] - zp);
  o[6] = f2bf((float)b[2] - zp); o[7] = f2bf((float)b[3] - zp);
  *(u16x8*)(out + 8 * i) = o;
}

// Stage one half-tile (128 rows x 64 bf16 = 16KB): 8 waves x 2 chunks x 1KB.
__device__ __forceinline__ void stage2(const char* s0, const char* s1, char* ldsT,
                                       int h, int Ti, int chunk0, int chunk1) {
  const size_t off = (size_t)Ti * 128 + (size_t)h * 1048576;
  __builtin_amdgcn_global_load_lds(
      (const __attribute__((address_space(1))) void*)(s0 + off),
      (__attribute__((address_space(3))) void*)(ldsT + h * 16384 + chunk0), 16, 0, 0);
  __builtin_amdgcn_global_load_lds(
      (const __attribute__((address_space(1))) void*)(s1 + off),
      (__attribute__((address_space(3))) void*)(ldsT + h * 16384 + chunk1), 16, 0, 0);
}

// One K-tile = 2 barrier intervals of 32 MFMA each; reads in consumption
// order; compiler-managed counted lgkm waits overlap LDS service with MFMA.
__device__ __forceinline__ void ktile(
    int T,
    const char* paK0, const char* paK1, const char* pbK0, const char* pbK1,
    char* stA, char* stB,
    const char* srcA0, const char* srcA1, const char* srcB0, const char* srcB1,
    int chunk0, int chunk1, f32x4 (&acc)[8][4]) {
  bf16x8 af[4][2], b0f[2][2], b1f[2][2];

  // ==== interval 1: reads (consumption order); stage B(T+1); bar; Q00+Q01 ====
  af[0][0]  = *(const bf16x8*)(paK0);
  af[0][1]  = *(const bf16x8*)(paK1);
  b0f[0][0] = *(const bf16x8*)(pbK0);
  b0f[0][1] = *(const bf16x8*)(pbK1);
  b0f[1][0] = *(const bf16x8*)(pbK0 + 2048);
  b0f[1][1] = *(const bf16x8*)(pbK1 + 2048);
  af[1][0]  = *(const bf16x8*)(paK0 + 2048);
  af[1][1]  = *(const bf16x8*)(paK1 + 2048);
  af[2][0]  = *(const bf16x8*)(paK0 + 4096);
  af[2][1]  = *(const bf16x8*)(paK1 + 4096);
  af[3][0]  = *(const bf16x8*)(paK0 + 6144);
  af[3][1]  = *(const bf16x8*)(paK1 + 6144);
  b1f[0][0] = *(const bf16x8*)(pbK0 + 4096);
  b1f[0][1] = *(const bf16x8*)(pbK1 + 4096);
  b1f[1][0] = *(const bf16x8*)(pbK0 + 6144);
  b1f[1][1] = *(const bf16x8*)(pbK1 + 6144);
  if (T < NT - 1) {
    stage2(srcB0, srcB1, stB, 0, T + 1, chunk0, chunk1);
    stage2(srcB0, srcB1, stB, 1, T + 1, chunk0, chunk1);
  }
  __builtin_amdgcn_s_barrier();
  FENCE();
  __builtin_amdgcn_s_setprio(1);
#pragma unroll
  for (int fi = 0; fi < 4; ++fi)
#pragma unroll
    for (int fj = 0; fj < 2; ++fj) {
      acc[fi][fj] = MFMA16(af[fi][0], b0f[fj][0], acc[fi][fj]);
      acc[fi][fj] = MFMA16(af[fi][1], b0f[fj][1], acc[fi][fj]);
    }
#pragma unroll
  for (int fi = 0; fi < 4; ++fi)
#pragma unroll
    for (int fj = 0; fj < 2; ++fj) {
      acc[fi][2 + fj] = MFMA16(af[fi][0], b1f[fj][0], acc[fi][2 + fj]);
      acc[fi][2 + fj] = MFMA16(af[fi][1], b1f[fj][1], acc[fi][2 + fj]);
    }
  __builtin_amdgcn_s_setprio(0);

  // ==== interval 2: reads a_hi; stage A(T+2); vmcnt; bar; Q11+Q10 ====
  af[0][0] = *(const bf16x8*)(paK0 + 8192);
  af[0][1] = *(const bf16x8*)(paK1 + 8192);
  af[1][0] = *(const bf16x8*)(paK0 + 8192 + 2048);
  af[1][1] = *(const bf16x8*)(paK1 + 8192 + 2048);
  af[2][0] = *(const bf16x8*)(paK0 + 8192 + 4096);
  af[2][1] = *(const bf16x8*)(paK1 + 8192 + 4096);
  af[3][0] = *(const bf16x8*)(paK0 + 8192 + 6144);
  af[3][1] = *(const bf16x8*)(paK1 + 8192 + 6144);
  if (T < NT - 2) {
    stage2(srcA0, srcA1, stA, 0, T + 2, chunk0, chunk1);
    stage2(srcA0, srcA1, stA, 1, T + 2, chunk0, chunk1);
  }
  // Publishes tile T+1 (drains A(T+1)+B(T+1); leaves A(T+2) in flight).
  if (T < NT - 2) asm volatile("s_waitcnt vmcnt(4)" ::: "memory");
  else            asm volatile("s_waitcnt vmcnt(0)" ::: "memory");
  __builtin_amdgcn_s_barrier();
  FENCE();
  __builtin_amdgcn_s_setprio(1);
#pragma unroll
  for (int fi = 0; fi < 4; ++fi)
#pragma unroll
    for (int fj = 0; fj < 2; ++fj) {
      acc[4 + fi][2 + fj] = MFMA16(af[fi][0], b1f[fj][0], acc[4 + fi][2 + fj]);
      acc[4 + fi][2 + fj] = MFMA16(af[fi][1], b1f[fj][1], acc[4 + fi][2 + fj]);
    }
#pragma unroll
  for (int fi = 0; fi < 4; ++fi)
#pragma unroll
    for (int fj = 0; fj < 2; ++fj) {
      acc[4 + fi][fj] = MFMA16(af[fi][0], b0f[fj][0], acc[4 + fi][fj]);
      acc[4 + fi][fj] = MFMA16(af[fi][1], b0f[fj][1], acc[4 + fi][fj]);
    }
  __builtin_amdgcn_s_setprio(0);
}

// ---- 256x256 GEMM, 2 intervals/K-tile, A 3-buf + B 2-buf (160KB LDS) ----
__global__ __launch_bounds__(512, 2) void gemm8_kernel(
    const unsigned short* __restrict__ A, const unsigned short* __restrict__ B,
    const float* __restrict__ scale_ptr, const float* __restrict__ bias,
    float* __restrict__ C) {
  __shared__ __align__(16) char lds[163840];  // A0,A1,A2 @0/32K/64K; B0,B1 @96K/128K

  const int t = threadIdx.x;
  const int lane = t & 63;
  const int w = t >> 6;      // 0..7
  const int wm = w >> 2;     // 0..1
  const int wn = w & 3;      // 0..3
  const int ll = lane & 15;
  const int lh = lane >> 4;

  // T1: bijective XCD swizzle (nwg = 512, 512 % 8 == 0)
  const int nwg = gridDim.x * gridDim.y;
  const int flat = blockIdx.y * gridDim.x + blockIdx.x;
  const int per = nwg >> 3;
  const int sw = (flat & 7) * per + (flat >> 3);
  const int tn = sw & (N_DIM / BN - 1);
  const int tm = sw / (N_DIM / BN);
  const size_t gm0 = (size_t)tm * BM;
  const size_t gn0 = (size_t)tn * BN;

  char* lA0 = (char*)lds;
  char* lA1 = (char*)lds + 32768;
  char* lA2 = (char*)lds + 65536;
  char* lB0 = (char*)lds + 98304;
  char* lB1 = (char*)lds + 131072;

  // Fragment-read bases (swizzle folded to per-thread constants).
  const int sbase = (lh * 16) ^ ((ll & 7) << 4);
  const int aoff = wm * 16384 + ll * 128;
  const int boff = wn * 8192 + ll * 128;
  const char* pA0k0 = lA0 + aoff + sbase;  const char* pA0k1 = lA0 + aoff + (sbase ^ 64);
  const char* pA1k0 = lA1 + aoff + sbase;  const char* pA1k1 = lA1 + aoff + (sbase ^ 64);
  const char* pA2k0 = lA2 + aoff + sbase;  const char* pA2k1 = lA2 + aoff + (sbase ^ 64);
  const char* pB0k0 = lB0 + boff + sbase;  const char* pB0k1 = lB0 + boff + (sbase ^ 64);
  const char* pB1k0 = lB1 + boff + sbase;  const char* pB1k1 = lB1 + boff + (sbase ^ 64);

  // Staging: per-thread inverse-swizzled row/col constants.
  const int rowS0 = w * 16 + (lane >> 3);
  const int rowS1 = w * 16 + 8 + (lane >> 3);
  const int colSB = ((lane & 7) * 16) ^ (((lane >> 3) & 7) << 4);
  const int chunk0 = w * 2048;
  const int chunk1 = w * 2048 + 1024;
  const char* srcA0 = (const char*)A + (gm0 + rowS0) * (size_t)(K_DIM * 2) + colSB;
  const char* srcA1 = (const char*)A + (gm0 + rowS1) * (size_t)(K_DIM * 2) + colSB;
  const char* srcB0 = (const char*)B + (gn0 + rowS0) * (size_t)(K_DIM * 2) + colSB;
  const char* srcB1 = (const char*)B + (gn0 + rowS1) * (size_t)(K_DIM * 2) + colSB;

  f32x4 acc[8][4] = {};  // [mh*4+fi][nh*2+fj]

  // ---- prologue: A(0)->A0, B(0)->B0, A(1)->A1 (12 loads) ----
  stage2(srcA0, srcA1, lA0, 0, 0, chunk0, chunk1);
  stage2(srcA0, srcA1, lA0, 1, 0, chunk0, chunk1);
  stage2(srcB0, srcB1, lB0, 0, 0, chunk0, chunk1);
  stage2(srcB0, srcB1, lB0, 1, 0, chunk0, chunk1);
  stage2(srcA0, srcA1, lA1, 0, 1, chunk0, chunk1);
  stage2(srcA0, srcA1, lA1, 1, 1, chunk0, chunk1);
  asm volatile("s_waitcnt vmcnt(4)" ::: "memory");  // A0,B0 landed; A1 in flight
  __builtin_amdgcn_s_barrier();
  FENCE();

  // Buffer rotation period 6: tile T reads A[T%3], B[T%2];
  // stages B(T+1)->B[(T+1)%2], A(T+2)->A[(T+2)%3].
  for (int T6 = 0; T6 < NT - 4; T6 += 6) {
    ktile(T6 + 0, pA0k0, pA0k1, pB0k0, pB0k1, lA2, lB1, srcA0, srcA1, srcB0, srcB1, chunk0, chunk1, acc);
    ktile(T6 + 1, pA1k0, pA1k1, pB1k0, pB1k1, lA0, lB0, srcA0, srcA1, srcB0, srcB1, chunk0, chunk1, acc);
    ktile(T6 + 2, pA2k0, pA2k1, pB0k0, pB0k1, lA1, lB1, srcA0, srcA1, srcB0, srcB1, chunk0, chunk1, acc);
    ktile(T6 + 3, pA0k0, pA0k1, pB1k0, pB1k1, lA2, lB0, srcA0, srcA1, srcB0, srcB1, chunk0, chunk1, acc);
    ktile(T6 + 4, pA1k0, pA1k1, pB0k0, pB0k1, lA0, lB1, srcA0, srcA1, srcB0, srcB1, chunk0, chunk1, acc);
    ktile(T6 + 5, pA2k0, pA2k1, pB1k0, pB1k1, lA1, lB0, srcA0, srcA1, srcB0, srcB1, chunk0, chunk1, acc);
  }
  // tail: T = 60..63 (60 % 6 == 0)
  ktile(NT - 4, pA0k0, pA0k1, pB0k0, pB0k1, lA2, lB1, srcA0, srcA1, srcB0, srcB1, chunk0, chunk1, acc);
  ktile(NT - 3, pA1k0, pA1k1, pB1k0, pB1k1, lA0, lB0, srcA0, srcA1, srcB0, srcB1, chunk0, chunk1, acc);
  ktile(NT - 2, pA2k0, pA2k1, pB0k0, pB0k1, lA1, lB1, srcA0, srcA1, srcB0, srcB1, chunk0, chunk1, acc);
  ktile(NT - 1, pA0k0, pA0k1, pB1k0, pB1k1, lA2, lB0, srcA0, srcA1, srcB0, srcB1, chunk0, chunk1, acc);

  // ---- epilogue: y = scale*acc + bias ----
  const float sc = *scale_ptr;
#pragma unroll
  for (int nh = 0; nh < 2; ++nh)
#pragma unroll
    for (int fj = 0; fj < 2; ++fj) {
      const size_t col = gn0 + wn * 64 + nh * 32 + fj * 16 + ll;
      const float bv = bias[col];
#pragma unroll
      for (int mh = 0; mh < 2; ++mh)
#pragma unroll
        for (int fi = 0; fi < 4; ++fi) {
          const size_t row0 = gm0 + wm * 128 + mh * 64 + fi * 16 + lh * 4;
          const f32x4 v = acc[mh * 4 + fi][nh * 2 + fj];
#pragma unroll
          for (int r = 0; r < 4; ++r)
            C[(row0 + r) * N_DIM + col] = sc * v[r] + bv;
        }
    }
}

// ---- fallback (small ws): fused-conversion 128^2 GEMM, known-correct from R0 ----
__global__ __launch_bounds__(256, 2) void gemm_fallback_kernel(
    const float* __restrict__ Aptr, const int* __restrict__ Wptr,
    const float* __restrict__ scale_ptr, const float* __restrict__ zp_ptr,
    const float* __restrict__ bias, float* __restrict__ C) {
  __shared__ unsigned short As[128 * 32];
  __shared__ unsigned short Ws[128 * 32];
  const int t = threadIdx.x;
  const int lane = t & 63;
  const int w = t >> 6;
  const int wm = w >> 1, wn = w & 1;
  const size_t gm0 = (size_t)blockIdx.y * 128;
  const size_t gn0 = (size_t)blockIdx.x * 128;
  f32x4 acc[4][4] = {};
  const float zp = *zp_ptr;
  for (int k0 = 0; k0 < K_DIM; k0 += 32) {
    __syncthreads();
    const int row = t >> 1;
    const int kh = (t & 1) * 16;
    const float* sa = Aptr + (gm0 + row) * (size_t)K_DIM + k0 + kh;
    f32x4 a0 = ((const f32x4*)sa)[0], a1 = ((const f32x4*)sa)[1];
    f32x4 a2 = ((const f32x4*)sa)[2], a3 = ((const f32x4*)sa)[3];
    u16x8 o0, o1;
    o0[0] = f2bf(a0[0]); o0[1] = f2bf(a0[1]); o0[2] = f2bf(a0[2]); o0[3] = f2bf(a0[3]);
    o0[4] = f2bf(a1[0]); o0[5] = f2bf(a1[1]); o0[6] = f2bf(a1[2]); o0[7] = f2bf(a1[3]);
    o1[0] = f2bf(a2[0]); o1[1] = f2bf(a2[1]); o1[2] = f2bf(a2[2]); o1[3] = f2bf(a2[3]);
    o1[4] = f2bf(a3[0]); o1[5] = f2bf(a3[1]); o1[6] = f2bf(a3[2]); o1[7] = f2bf(a3[3]);
    *(u16x8*)&As[row * 32 + kh] = o0;
    *(u16x8*)&As[row * 32 + kh + 8] = o1;
    const int* sw = Wptr + (gn0 + row) * (size_t)K_DIM + k0 + kh;
    i32x4 w0 = ((const i32x4*)sw)[0], w1 = ((const i32x4*)sw)[1];
    i32x4 w2 = ((const i32x4*)sw)[2], w3 = ((const i32x4*)sw)[3];
    u16x8 p0, p1;
    p0[0] = f2bf((float)w0[0] - zp); p0[1] = f2bf((float)w0[1] - zp);
    p0[2] = f2bf((float)w0[2] - zp); p0[3] = f2bf((float)w0[3] - zp);
    p0[4] = f2bf((float)w1[0] - zp); p0[5] = f2bf((float)w1[1] - zp);
    p0[6] = f2bf((float)w1[2] - zp); p0[7] = f2bf((float)w1[3] - zp);
    p1[0] = f2bf((float)w2[0] - zp); p1[1] = f2bf((float)w2[1] - zp);
    p1[2] = f2bf((float)w2[2] - zp); p1[3] = f2bf((float)w2[3] - zp);
    p1[4] = f2bf((float)w3[0] - zp); p1[5] = f2bf((float)w3[1] - zp);
    p1[6] = f2bf((float)w3[2] - zp); p1[7] = f2bf((float)w3[3] - zp);
    *(u16x8*)&Ws[row * 32 + kh] = p0;
    *(u16x8*)&Ws[row * 32 + kh + 8] = p1;
    __syncthreads();
    bf16x8 af[4], bfr[4];
#pragma unroll
    for (int f = 0; f < 4; ++f) {
      af[f] = *(const bf16x8*)&As[(wm * 64 + f * 16 + (lane & 15)) * 32 + (lane >> 4) * 8];
      bfr[f] = *(const bf16x8*)&Ws[(wn * 64 + f * 16 + (lane & 15)) * 32 + (lane >> 4) * 8];
    }
#pragma unroll
    for (int i = 0; i < 4; ++i)
#pragma unroll
      for (int j = 0; j < 4; ++j)
        acc[i][j] = MFMA16(af[i], bfr[j], acc[i][j]);
  }
  const float sc = *scale_ptr;
#pragma unroll
  for (int i = 0; i < 4; ++i) {
    const int rbase = wm * 64 + i * 16 + ((lane >> 4) << 2);
#pragma unroll
    for (int j = 0; j < 4; ++j) {
      const size_t col = gn0 + wn * 64 + j * 16 + (lane & 15);
      const float bv = bias[col];
#pragma unroll
      for (int r = 0; r < 4; ++r)
        C[(gm0 + rbase + r) * N_DIM + col] = sc * acc[i][j][r] + bv;
    }
  }
}

extern "C" void kernel_launch(void* const* d_in, const int* in_sizes, int n_in,
                              void* d_out, int out_size, void* d_ws, size_t ws_size,
                              hipStream_t stream) {
  const float* x = (const float*)d_in[0];
  const int* q = (const int*)d_in[1];
  const float* scale = (const float*)d_in[2];
  const float* zp = (const float*)d_in[3];
  const float* bias = (const float*)d_in[4];
  float* out = (float*)d_out;

  const size_t needA = (size_t)M_DIM * K_DIM * 2;  // 64 MiB
  const size_t needW = (size_t)N_DIM * K_DIM * 2;  // 32 MiB

  if (ws_size >= needA + needW) {
    unsigned short* Abf = (unsigned short*)d_ws;
    unsigned short* Wbf = (unsigned short*)((char*)d_ws + needA);
    cvt_x_kernel<<<(M_DIM * (size_t)K_DIM) / (8 * 256), 256, 0, stream>>>(x, Abf);
    cvt_w_kernel<<<(N_DIM * (size_t)K_DIM) / (8 * 256), 256, 0, stream>>>(q, zp, Wbf);
    dim3 grid(N_DIM / BN, M_DIM / BM);  // 16 x 32 = 512
    gemm8_kernel<<<grid, 512, 0, stream>>>(Abf, Wbf, scale, bias, out);
  } else {
    dim3 grid(N_DIM / 128, M_DIM / 128);
    gemm_fallback_kernel<<<grid, 256, 0, stream>>>(x, q, scale, zp, bias, out);
  }
}